// Round 18
// baseline (838.751 us; speedup 1.0000x reference)
//
#include <hip/hip_runtime.h>
#include <cstdint>
#include <cmath>

#define BN_ 4
#define NPTS 2048
#define KNB 20
#define TOTP (BN_ * NPTS)   // 8192
#define PFSZ ((size_t)TOTP * 1024)

// ---------------- transpose x (B,3,N) -> P0 (B*N, 3)
__global__ void k_transpose(const float* __restrict__ x, float* __restrict__ P0) {
  int i = blockIdx.x * 256 + threadIdx.x;
  if (i >= TOTP) return;
  int b = i / NPTS, n = i % NPTS;
#pragma unroll
  for (int c = 0; c < 3; ++c)
    P0[i * 3 + c] = x[((size_t)b * 3 + c) * NPTS + n];
}

// ---------------- squared norms per point
__global__ void k_sqnorm(const float* __restrict__ base, int ld, int C, float* __restrict__ xx) {
  int i = blockIdx.x * 256 + threadIdx.x;
  if (i >= TOTP) return;
  const float* r = base + (size_t)i * ld;
  float s = 0.f;
  for (int c = 0; c < C; ++c) s = fmaf(r[c], r[c], s);
  xx[i] = s;
}

// ---------------- Symmetric Gram, float4-scalar register prefetch, (256,2) (== R17,
// bitwise-frozen: feeds KNN)
__global__ __launch_bounds__(256, 2) void k_gram128(const float* __restrict__ A_all, int lda,
                                                    int K, float* __restrict__ G4) {
  __shared__ float As[2][8][128];
  __shared__ float Bs[2][8][128];
  const int T = NPTS / 128;  // 16
  int q = blockIdx.x;
  int bi = 0;
  while (q >= T - bi) { q -= T - bi; ++bi; }
  int bj = bi + q;
  int b = blockIdx.z;
  const float* A = A_all + (size_t)b * NPTS * lda;
  float* G = G4 + (size_t)b * NPTS * NPTS;
  int tid = threadIdx.x;
  int i0 = bi * 128, m0 = bj * 128;
  int tx = tid & 15, ty = tid >> 4;
  int lr = tid >> 1;          // 0..127
  int lc = (tid & 1) * 4;     // 0 or 4
  const float* Arow = A + (size_t)(i0 + lr) * lda;
  const float* Brow = A + (size_t)(m0 + lr) * lda;
  float acc[2][2][4][4] = {};
  float4 pa, pb;

  pa = *(const float4*)(Arow + lc);
  pb = *(const float4*)(Brow + lc);
  As[0][lc + 0][lr] = pa.x; As[0][lc + 1][lr] = pa.y;
  As[0][lc + 2][lr] = pa.z; As[0][lc + 3][lr] = pa.w;
  Bs[0][lc + 0][lr] = pb.x; Bs[0][lc + 1][lr] = pb.y;
  Bs[0][lc + 2][lr] = pb.z; Bs[0][lc + 3][lr] = pb.w;
  __syncthreads();
  for (int k0 = 0; k0 < K; k0 += 8) {
    int cur = (k0 >> 3) & 1;
    bool more = (k0 + 8 < K);
    if (more) {
      pa = *(const float4*)(Arow + k0 + 8 + lc);
      pb = *(const float4*)(Brow + k0 + 8 + lc);
    }
#pragma unroll
    for (int k = 0; k < 8; ++k) {
      float4 a0 = *(const float4*)&As[cur][k][ty * 4];
      float4 a1 = *(const float4*)&As[cur][k][64 + ty * 4];
      float4 b0 = *(const float4*)&Bs[cur][k][tx * 4];
      float4 b1 = *(const float4*)&Bs[cur][k][64 + tx * 4];
      float ar[2][4] = {{a0.x, a0.y, a0.z, a0.w}, {a1.x, a1.y, a1.z, a1.w}};
      float br[2][4] = {{b0.x, b0.y, b0.z, b0.w}, {b1.x, b1.y, b1.z, b1.w}};
#pragma unroll
      for (int gi = 0; gi < 2; ++gi)
#pragma unroll
        for (int gj = 0; gj < 2; ++gj)
#pragma unroll
          for (int ii = 0; ii < 4; ++ii)
#pragma unroll
            for (int jj = 0; jj < 4; ++jj)
              acc[gi][gj][ii][jj] = fmaf(ar[gi][ii], br[gj][jj], acc[gi][gj][ii][jj]);
    }
    if (more) {
      int nxt = cur ^ 1;
      As[nxt][lc + 0][lr] = pa.x; As[nxt][lc + 1][lr] = pa.y;
      As[nxt][lc + 2][lr] = pa.z; As[nxt][lc + 3][lr] = pa.w;
      Bs[nxt][lc + 0][lr] = pb.x; Bs[nxt][lc + 1][lr] = pb.y;
      Bs[nxt][lc + 2][lr] = pb.z; Bs[nxt][lc + 3][lr] = pb.w;
    }
    __syncthreads();
  }
#pragma unroll
  for (int gi = 0; gi < 2; ++gi)
#pragma unroll
    for (int ii = 0; ii < 4; ++ii) {
      int row = i0 + gi * 64 + ty * 4 + ii;
      float* cr = G + (size_t)row * NPTS + m0;
#pragma unroll
      for (int gj = 0; gj < 2; ++gj) {
        float4 vv = {acc[gi][gj][ii][0], acc[gi][gj][ii][1],
                     acc[gi][gj][ii][2], acc[gi][gj][ii][3]};
        *(float4*)(cr + gj * 64 + tx * 4) = vv;
      }
    }
  if (bi != bj) {
#pragma unroll
    for (int gj = 0; gj < 2; ++gj)
#pragma unroll
      for (int jj = 0; jj < 4; ++jj) {
        int col = m0 + gj * 64 + tx * 4 + jj;
#pragma unroll
        for (int gi = 0; gi < 2; ++gi) {
          float4 vv = {acc[gi][gj][0][jj], acc[gi][gj][1][jj],
                       acc[gi][gj][2][jj], acc[gi][gj][3][jj]};
          *(float4*)(G + (size_t)col * NPTS + i0 + gi * 64 + ty * 4) = vv;
        }
      }
  }
}

// ---------------- Final GEMM, split-K=2: grid.z selects K half [z*256,(z+1)*256),
// writes partial into Cout + z*PFSZ. Consumers sum the two halves on the fly
// (fixed-order, deterministic). PF feeds only outputs (not KNN) -> ulp-level change
// is safe vs the 0.246 threshold. Register profile identical to R14's proven kernel.
__global__ __launch_bounds__(256, 2) void k_gemm128(const float* __restrict__ A, int lda, int K,
                                                    const float* __restrict__ W,
                                                    float* __restrict__ Cout, int ldc) {
  __shared__ float As[2][8][128];
  __shared__ float Bs[2][8][128];
  int tid = threadIdx.x;
  int i0 = blockIdx.y * 128, j0 = blockIdx.x * 128;
  int kBegin = blockIdx.z * 256, kEnd = kBegin + 256;
  float* Cpart = Cout + (size_t)blockIdx.z * PFSZ;
  int tx = tid & 15, ty = tid >> 4;
  int lr = tid >> 1;
  int lc = (tid & 1) * 4;
  const float* Arow = A + (size_t)(i0 + lr) * lda;
  const float* Wrow = W + (size_t)(j0 + lr) * K;
  float acc[2][2][4][4] = {};
  float4 pa, pw;

  pa = *(const float4*)(Arow + kBegin + lc);
  pw = *(const float4*)(Wrow + kBegin + lc);
  As[0][lc + 0][lr] = pa.x; As[0][lc + 1][lr] = pa.y;
  As[0][lc + 2][lr] = pa.z; As[0][lc + 3][lr] = pa.w;
  Bs[0][lc + 0][lr] = pw.x; Bs[0][lc + 1][lr] = pw.y;
  Bs[0][lc + 2][lr] = pw.z; Bs[0][lc + 3][lr] = pw.w;
  __syncthreads();
  for (int k0 = kBegin; k0 < kEnd; k0 += 8) {
    int cur = ((k0 - kBegin) >> 3) & 1;
    bool more = (k0 + 8 < kEnd);
    if (more) {
      pa = *(const float4*)(Arow + k0 + 8 + lc);
      pw = *(const float4*)(Wrow + k0 + 8 + lc);
    }
#pragma unroll
    for (int k = 0; k < 8; ++k) {
      float4 a0 = *(const float4*)&As[cur][k][ty * 4];
      float4 a1 = *(const float4*)&As[cur][k][64 + ty * 4];
      float4 b0 = *(const float4*)&Bs[cur][k][tx * 4];
      float4 b1 = *(const float4*)&Bs[cur][k][64 + tx * 4];
      float ar[2][4] = {{a0.x, a0.y, a0.z, a0.w}, {a1.x, a1.y, a1.z, a1.w}};
      float br[2][4] = {{b0.x, b0.y, b0.z, b0.w}, {b1.x, b1.y, b1.z, b1.w}};
#pragma unroll
      for (int gi = 0; gi < 2; ++gi)
#pragma unroll
        for (int gj = 0; gj < 2; ++gj)
#pragma unroll
          for (int ii = 0; ii < 4; ++ii)
#pragma unroll
            for (int jj = 0; jj < 4; ++jj)
              acc[gi][gj][ii][jj] = fmaf(ar[gi][ii], br[gj][jj], acc[gi][gj][ii][jj]);
    }
    if (more) {
      int nxt = cur ^ 1;
      As[nxt][lc + 0][lr] = pa.x; As[nxt][lc + 1][lr] = pa.y;
      As[nxt][lc + 2][lr] = pa.z; As[nxt][lc + 3][lr] = pa.w;
      Bs[nxt][lc + 0][lr] = pw.x; Bs[nxt][lc + 1][lr] = pw.y;
      Bs[nxt][lc + 2][lr] = pw.z; Bs[nxt][lc + 3][lr] = pw.w;
    }
    __syncthreads();
  }
#pragma unroll
  for (int gi = 0; gi < 2; ++gi)
#pragma unroll
    for (int ii = 0; ii < 4; ++ii) {
      int row = i0 + gi * 64 + ty * 4 + ii;
      float* cr = Cpart + (size_t)row * ldc + j0;
#pragma unroll
      for (int gj = 0; gj < 2; ++gj) {
        float4 vv = {acc[gi][gj][ii][0], acc[gi][gj][ii][1],
                     acc[gi][gj][ii][2], acc[gi][gj][ii][3]};
        *(float4*)(cr + gj * 64 + tx * 4) = vv;
      }
    }
}

// ---------------- GEMM 64Mx128N, 4x8 micro, BK=8 dbuf (layer GEMMs; bitwise-frozen)
__global__ __launch_bounds__(256, 4) void k_gemm64(const float* __restrict__ A, int lda, int K,
                                                   const float* __restrict__ W, int mode, int O,
                                                   int twoC, float* __restrict__ Cout, int ldc) {
  __shared__ float As[2][8][64];
  __shared__ float Bs[2][8][128];
  int tid = threadIdx.x;
  int i0 = blockIdx.y * 64, j0 = blockIdx.x * 128;
  int tx = tid & 15, ty = tid >> 4;
  int lrB = tid >> 1;
  int lcB = (tid & 1) * 4;
  int lrA = tid >> 2;
  int lcA = (tid & 3) * 2;
  const float* ArowA = A + (size_t)(i0 + lrA) * lda;
  int j = j0 + lrB;
  float acc[2][4][4] = {};

  auto stage = [&](int buf, int k0) {
    if ((lda & 1) == 0 && k0 + lcA + 2 <= K) {
      float2 av = *(const float2*)(ArowA + k0 + lcA);
      As[buf][lcA + 0][lrA] = av.x;
      As[buf][lcA + 1][lrA] = av.y;
    } else {
#pragma unroll
      for (int u = 0; u < 2; ++u) {
        int k = k0 + lcA + u;
        As[buf][lcA + u][lrA] = (k < K) ? ArowA[k] : 0.f;
      }
    }
#pragma unroll
    for (int u = 0; u < 4; ++u) {
      int k = k0 + lcB + u;
      float wv = 0.f;
      if (k < K) {
        if (mode == 0) wv = W[(size_t)j * K + k];
        else if (j < O) wv = W[(size_t)j * twoC + k];
        else { const float* wr = W + (size_t)(j - O) * twoC; wv = wr[K + k] - wr[k]; }
      }
      Bs[buf][lcB + u][lrB] = wv;
    }
  };

  stage(0, 0);
  __syncthreads();
  for (int k0 = 0; k0 < K; k0 += 8) {
    int cur = (k0 >> 3) & 1;
    if (k0 + 8 < K) stage(cur ^ 1, k0 + 8);
#pragma unroll
    for (int k = 0; k < 8; ++k) {
      float4 a0 = *(const float4*)&As[cur][k][ty * 4];
      float4 b0 = *(const float4*)&Bs[cur][k][tx * 4];
      float4 b1 = *(const float4*)&Bs[cur][k][64 + tx * 4];
      float ar[4] = {a0.x, a0.y, a0.z, a0.w};
      float br[2][4] = {{b0.x, b0.y, b0.z, b0.w}, {b1.x, b1.y, b1.z, b1.w}};
#pragma unroll
      for (int gj = 0; gj < 2; ++gj)
#pragma unroll
        for (int ii = 0; ii < 4; ++ii)
#pragma unroll
          for (int jj = 0; jj < 4; ++jj)
            acc[gj][ii][jj] = fmaf(ar[ii], br[gj][jj], acc[gj][ii][jj]);
    }
    __syncthreads();
  }
#pragma unroll
  for (int ii = 0; ii < 4; ++ii) {
    int row = i0 + ty * 4 + ii;
    float* cr = Cout + (size_t)row * ldc + j0;
#pragma unroll
    for (int gj = 0; gj < 2; ++gj) {
      float4 vv = {acc[gj][ii][0], acc[gj][ii][1], acc[gj][ii][2], acc[gj][ii][3]};
      *(float4*)(cr + gj * 64 + tx * 4) = vv;
    }
  }
}

// ---------------- top-20 (layers 2-4): register-resident (bitwise-frozen)
__global__ __launch_bounds__(256) void k_topk(const float* __restrict__ G4,
                                              const float* __restrict__ xx,
                                              int* __restrict__ idx) {
  int tid = threadIdx.x, w = tid >> 6, lane = tid & 63;
  int b = blockIdx.y;
  int n = blockIdx.x * 4 + w;
  const float* Gr = G4 + (size_t)b * NPTS * NPTS + (size_t)n * NPTS;
  const float* xxb = xx + b * NPTS;
  int* idxb = idx + ((size_t)b * NPTS + n) * KNB;
  float xn = xxb[n];
  float v[32];
#pragma unroll
  for (int t = 0; t < 32; ++t) {
    int m = lane + (t << 6);
    v[t] = 2.f * Gr[m] - xn - xxb[m];
  }
  for (int r = 0; r < KNB; ++r) {
    float bv = v[0]; int bt = 0;
#pragma unroll
    for (int t = 1; t < 32; ++t)
      if (v[t] > bv) { bv = v[t]; bt = t; }
    int bm = lane + (bt << 6);
    float cv = bv; int cm = bm;
#pragma unroll
    for (int off = 32; off; off >>= 1) {
      float ov = __shfl_xor(cv, off, 64);
      int om = __shfl_xor(cm, off, 64);
      if (ov > cv || (ov == cv && om < cm)) { cv = ov; cm = om; }
    }
    if (lane == 0) idxb[r] = cm;
    bool mine = (cm == bm);
#pragma unroll
    for (int t = 0; t < 32; ++t)
      if (mine && t == bt) v[t] = -__builtin_inff();
  }
}

// ---------------- top-20 for layer 1 (K=3): direct distance (bitwise-frozen)
__global__ __launch_bounds__(256) void k_topk3(const float* __restrict__ P0,
                                               const float* __restrict__ xx,
                                               int* __restrict__ idx) {
  int tid = threadIdx.x, w = tid >> 6, lane = tid & 63;
  int b = blockIdx.y;
  int n = blockIdx.x * 4 + w;
  const float* Pb = P0 + (size_t)b * NPTS * 3;
  const float* xxb = xx + b * NPTS;
  int* idxb = idx + ((size_t)b * NPTS + n) * KNB;
  float xn0 = Pb[n * 3 + 0], xn1 = Pb[n * 3 + 1], xn2 = Pb[n * 3 + 2];
  float xn = xxb[n];
  float v[32];
#pragma unroll
  for (int t = 0; t < 32; ++t) {
    int m = lane + (t << 6);
    const float* pm = Pb + m * 3;
    float dot = fmaf(xn2, pm[2], fmaf(xn1, pm[1], fmaf(xn0, pm[0], 0.f)));
    v[t] = 2.f * dot - xn - xxb[m];
  }
  for (int r = 0; r < KNB; ++r) {
    float bv = v[0]; int bt = 0;
#pragma unroll
    for (int t = 1; t < 32; ++t)
      if (v[t] > bv) { bv = v[t]; bt = t; }
    int bm = lane + (bt << 6);
    float cv = bv; int cm = bm;
#pragma unroll
    for (int off = 32; off; off >>= 1) {
      float ov = __shfl_xor(cv, off, 64);
      int om = __shfl_xor(cm, off, 64);
      if (ov > cv || (ov == cv && om < cm)) { cv = ov; cm = om; }
    }
    if (lane == 0) idxb[r] = cm;
    bool mine = (cm == bm);
#pragma unroll
    for (int t = 0; t < 32; ++t)
      if (mine && t == bt) v[t] = -__builtin_inff();
  }
}

// ---------------- gather neighbors (frozen)
__global__ void k_gather(const float* __restrict__ YS, int twoO, int O,
                         const int* __restrict__ idx,
                         float* __restrict__ hmax, float* __restrict__ hmin,
                         double* __restrict__ Pbuf, double* __restrict__ Qbuf) {
  __shared__ float ps[4][256];
  __shared__ float pq[4][256];
  int tid = threadIdx.x, w = tid >> 6, lane = tid & 63;
  int i = blockIdx.x * 4 + w;
  int b = i / NPTS;
  int Q = O >> 6;  // 1,1,2,4
  float s[4], hx[4], hn[4], sm[4], sq[4];
  const float* Srow = YS + (size_t)i * twoO + O;
#pragma unroll
  for (int q = 0; q < 4; ++q) {
    if (q < Q) s[q] = Srow[lane + 64 * q];
    hx[q] = -__builtin_inff(); hn[q] = __builtin_inff(); sm[q] = 0.f; sq[q] = 0.f;
  }
  const int* ip = idx + (size_t)i * KNB;
  for (int k = 0; k < KNB; ++k) {
    int m = ip[k];
    const float* Yrow = YS + (size_t)(b * NPTS + m) * twoO;
#pragma unroll
    for (int q = 0; q < 4; ++q) {
      if (q < Q) {
        float h = Yrow[lane + 64 * q] + s[q];
        hx[q] = fmaxf(hx[q], h);
        hn[q] = fminf(hn[q], h);
        sm[q] += h;
        sq[q] = fmaf(h, h, sq[q]);
      }
    }
  }
#pragma unroll
  for (int q = 0; q < 4; ++q) {
    if (q < Q) {
      int o = lane + 64 * q;
      hmax[(size_t)i * O + o] = hx[q];
      hmin[(size_t)i * O + o] = hn[q];
      ps[w][o] = sm[q];
      pq[w][o] = sq[q];
    }
  }
  __syncthreads();
  if (tid < O) {
    double t1 = (double)(ps[0][tid] + ps[1][tid] + ps[2][tid] + ps[3][tid]);
    double t2 = (double)(pq[0][tid] + pq[1][tid] + pq[2][tid] + pq[3][tid]);
    Pbuf[(size_t)tid * 2048 + blockIdx.x] = t1;
    Qbuf[(size_t)tid * 2048 + blockIdx.x] = t2;
  }
}

// ---------------- deterministic reduce of 2048 partials per channel (frozen)
__global__ __launch_bounds__(256) void k_redstats(const double* __restrict__ Pbuf,
                                                  const double* __restrict__ Qbuf,
                                                  const float* __restrict__ g,
                                                  const float* __restrict__ bb, float cnt,
                                                  float* __restrict__ scale,
                                                  float* __restrict__ shift) {
  __shared__ double s1[256], s2[256];
  int o = blockIdx.x, t = threadIdx.x;
  double a = 0.0, c = 0.0;
#pragma unroll
  for (int j = 0; j < 8; ++j) {
    a += Pbuf[(size_t)o * 2048 + t + 256 * j];
    c += Qbuf[(size_t)o * 2048 + t + 256 * j];
  }
  s1[t] = a; s2[t] = c;
  __syncthreads();
  for (int s = 128; s; s >>= 1) {
    if (t < s) { s1[t] += s1[t + s]; s2[t] += s2[t + s]; }
    __syncthreads();
  }
  if (t == 0) {
    double mean = s1[0] / (double)cnt;
    double var = s2[0] / (double)cnt - mean * mean;
    double sc = (double)g[o] / sqrt(var + 1e-5);
    scale[o] = (float)sc;
    shift[o] = (float)((double)bb[o] - mean * sc);
  }
}

// ---------------- apply BN+lrelu (frozen)
__global__ void k_apply(const float* __restrict__ hmax, const float* __restrict__ hmin,
                        const float* __restrict__ scale, const float* __restrict__ shift,
                        float* __restrict__ Fout, int O) {
  int t = blockIdx.x * 256 + threadIdx.x;
  int i = t / O, o = t % O;
  float sc = scale[o];
  float h = (sc >= 0.f) ? hmax[t] : hmin[t];
  float v = fmaf(sc, h, shift[o]);
  Fout[(size_t)i * 512 + o] = (v >= 0.f) ? v : 0.2f * v;
}

// ---------------- final BN partials over PF = PFa + PFb (fixed-order sum)
__global__ void k_fstats(const float* __restrict__ PF, double* __restrict__ Fb,
                         double* __restrict__ Qb) {
  int tid = threadIdx.x, bid = blockIdx.x;
  float sm[4] = {0.f, 0.f, 0.f, 0.f}, sq[4] = {0.f, 0.f, 0.f, 0.f};
  int r0 = bid * 128;
  for (int r = 0; r < 128; ++r) {
    const float* row = PF + (size_t)(r0 + r) * 1024;
#pragma unroll
    for (int q = 0; q < 4; ++q) {
      float v = row[tid + 256 * q] + row[tid + 256 * q + PFSZ];
      sm[q] += v;
      sq[q] = fmaf(v, v, sq[q]);
    }
  }
#pragma unroll
  for (int q = 0; q < 4; ++q) {
    int o = tid + 256 * q;
    Fb[(size_t)o * 64 + bid] = (double)sm[q];
    Qb[(size_t)o * 64 + bid] = (double)sq[q];
  }
}

// ---------------- deterministic reduce -> sc5/sh5 (frozen)
__global__ __launch_bounds__(64) void k_red5(const double* __restrict__ Fb,
                                             const double* __restrict__ Qb,
                                             const float* __restrict__ g,
                                             const float* __restrict__ bb,
                                             float* __restrict__ sc5, float* __restrict__ sh5) {
  __shared__ double s1[64], s2[64];
  int o = blockIdx.x, t = threadIdx.x;
  s1[t] = Fb[(size_t)o * 64 + t];
  s2[t] = Qb[(size_t)o * 64 + t];
  __syncthreads();
  for (int s = 32; s; s >>= 1) {
    if (t < s) { s1[t] += s1[t + s]; s2[t] += s2[t + s]; }
    __syncthreads();
  }
  if (t == 0) {
    double cnt = (double)TOTP;
    double mean = s1[0] / cnt;
    double var = s2[0] / cnt - mean * mean;
    double sc = (double)g[o] / sqrt(var + 1e-5);
    sc5[o] = (float)sc;
    sh5[o] = (float)((double)bb[o] - mean * sc);
  }
}

// ---------------- out0 over PF = PFa + PFb
__global__ void k_out0(const float* __restrict__ PF, const float* __restrict__ sc5,
                       const float* __restrict__ sh5, float* __restrict__ out0) {
  __shared__ float t[64][65];
  int b = blockIdx.z, p0 = blockIdx.y * 64, o0 = blockIdx.x * 64;
  int ol = threadIdx.x & 63, pg = threadIdx.x >> 6;
#pragma unroll
  for (int q = 0; q < 16; ++q) {
    int p = q * 4 + pg;
    size_t idx = ((size_t)(b * NPTS + p0 + p)) * 1024 + o0 + ol;
    t[p][ol] = PF[idx] + PF[idx + PFSZ];
  }
  __syncthreads();
#pragma unroll
  for (int q = 0; q < 16; ++q) {
    int oo = q * 4 + pg;
    int o = o0 + oo;
    float v = fmaf(sc5[o], t[ol][oo], sh5[o]);
    float a = (v >= 0.f) ? v : 0.2f * v;
    out0[((size_t)(b * 1024 + o)) * 128 + p0 + ol] = a;
  }
}

// ---------------- per-(b,nb,o) max over PF = PFa + PFb
__global__ void k_gmax(const float* __restrict__ PF, const float* __restrict__ sc5,
                       const float* __restrict__ sh5, float* __restrict__ tmpmax) {
  int b = blockIdx.z, nb = blockIdx.y;
  int o = blockIdx.x * 256 + threadIdx.x;
  const float* base = PF + ((size_t)(b * NPTS + nb * 128)) * 1024 + o;
  float sc = sc5[o], sh = sh5[o];
  float m0 = -__builtin_inff(), m1 = m0, m2 = m0, m3 = m0;
  for (int p = 0; p < 128; p += 4) {
    float v0 = base[(size_t)(p + 0) * 1024] + base[(size_t)(p + 0) * 1024 + PFSZ];
    float v1 = base[(size_t)(p + 1) * 1024] + base[(size_t)(p + 1) * 1024 + PFSZ];
    float v2 = base[(size_t)(p + 2) * 1024] + base[(size_t)(p + 2) * 1024 + PFSZ];
    float v3 = base[(size_t)(p + 3) * 1024] + base[(size_t)(p + 3) * 1024 + PFSZ];
    float a0 = fmaf(sc, v0, sh); a0 = (a0 >= 0.f) ? a0 : 0.2f * a0;
    float a1 = fmaf(sc, v1, sh); a1 = (a1 >= 0.f) ? a1 : 0.2f * a1;
    float a2 = fmaf(sc, v2, sh); a2 = (a2 >= 0.f) ? a2 : 0.2f * a2;
    float a3 = fmaf(sc, v3, sh); a3 = (a3 >= 0.f) ? a3 : 0.2f * a3;
    m0 = fmaxf(m0, a0); m1 = fmaxf(m1, a1);
    m2 = fmaxf(m2, a2); m3 = fmaxf(m3, a3);
  }
  tmpmax[(size_t)(b * 16 + nb) * 1024 + o] = fmaxf(fmaxf(m0, m1), fmaxf(m2, m3));
}

// ---------------- gout duplication (frozen)
__global__ void k_gdup(const float* __restrict__ tmpmax, float* __restrict__ gout) {
  __shared__ float t[16][65];
  int b = blockIdx.y, o0 = blockIdx.x * 64;
  int ol = threadIdx.x & 63, ng = threadIdx.x >> 6;
#pragma unroll
  for (int q = 0; q < 4; ++q) {
    int nb = q * 4 + ng;
    t[nb][ol] = tmpmax[(size_t)(b * 16 + nb) * 1024 + o0 + ol];
  }
  __syncthreads();
  int nb2 = threadIdx.x & 15, og = threadIdx.x >> 4;
#pragma unroll
  for (int q = 0; q < 4; ++q) {
    int oo = q * 16 + og;
    float v = t[nb2][oo];
    size_t base = ((size_t)(b * 2048) + o0 + oo) * 16 + nb2;
    gout[base] = v;
    gout[base + 1024 * 16] = v;
  }
}

extern "C" void kernel_launch(void* const* d_in, const int* in_sizes, int n_in,
                              void* d_out, int out_size, void* d_ws, size_t ws_size,
                              hipStream_t stream) {
  const float* x  = (const float*)d_in[0];
  const float* W1 = (const float*)d_in[1];
  const float* W2 = (const float*)d_in[2];
  const float* W3 = (const float*)d_in[3];
  const float* W4 = (const float*)d_in[4];
  const float* W5 = (const float*)d_in[5];
  const float* g1 = (const float*)d_in[6];  const float* b1 = (const float*)d_in[7];
  const float* g2 = (const float*)d_in[8];  const float* b2 = (const float*)d_in[9];
  const float* g3 = (const float*)d_in[10]; const float* b3 = (const float*)d_in[11];
  const float* g4 = (const float*)d_in[12]; const float* b4 = (const float*)d_in[13];
  const float* g5 = (const float*)d_in[14]; const float* b5 = (const float*)d_in[15];

  float* ws = (float*)d_ws;
  size_t off = 0;
  auto alloc = [&](size_t nfl) { float* p = ws + off; off += (nfl + 63) & ~(size_t)63; return p; };
  float*  P0   = alloc((size_t)TOTP * 3);
  float*  F    = alloc((size_t)TOTP * 512);
  float*  xx   = alloc(TOTP);
  // Union U (16.78M floats): G4 lives during gram+topk of layers 2-4;
  // YS/hmax/hmin live during gemm..apply; PF (split-K halves PFa|PFb, 2x8.39M)
  // occupies the whole U after the last topk.
  float*  U    = alloc((size_t)BN_ * NPTS * NPTS);
  float*  G4   = U;
  float*  YS   = U;
  float*  hmax = U + (size_t)TOTP * 512;
  float*  hmin = hmax + (size_t)TOTP * 256;
  float*  PF   = U;   // PFa = U[0..PFSZ), PFb = U[PFSZ..2*PFSZ)
  float*  tmpmax = alloc((size_t)BN_ * 16 * 1024);
  double* Pbuf = (double*)alloc((size_t)256 * 2048 * 2);
  double* Qbuf = (double*)alloc((size_t)256 * 2048 * 2);
  double* Fb   = (double*)alloc((size_t)1024 * 64 * 2);
  double* Qb   = (double*)alloc((size_t)1024 * 64 * 2);
  float*  scale= alloc(256);
  float*  shift= alloc(256);
  float*  sc5  = alloc(1024);
  float*  sh5  = alloc(1024);
  int*    idx  = (int*)alloc((size_t)TOTP * KNB);

  k_transpose<<<32, 256, 0, stream>>>(x, P0);

  struct L { const float* base; int lda, C, O, colout; const float* W; const float* g; const float* b; };
  L Ls[4] = {
    {P0,      3,   3,   64,  0,   W1, g1, b1},
    {F,       512, 64,  64,  64,  W2, g2, b2},
    {F + 64,  512, 64,  128, 128, W3, g3, b3},
    {F + 128, 512, 128, 256, 256, W4, g4, b4},
  };

  for (int l = 0; l < 4; ++l) {
    const L& a = Ls[l];
    k_sqnorm<<<32, 256, 0, stream>>>(a.base, a.lda, a.C, xx);
    if (l == 0) {
      k_topk3<<<dim3(512, BN_), 256, 0, stream>>>(P0, xx, idx);
    } else {
      k_gram128<<<dim3(136, 1, BN_), 256, 0, stream>>>(a.base, a.lda, a.C, G4);
      k_topk<<<dim3(512, BN_), 256, 0, stream>>>(G4, xx, idx);
    }
    int twoO = 2 * a.O;
    k_gemm64<<<dim3(twoO / 128, TOTP / 64), 256, 0, stream>>>(
        a.base, a.lda, a.C, a.W, 1, a.O, 2 * a.C, YS, twoO);
    k_gather<<<TOTP / 4, 256, 0, stream>>>(YS, twoO, a.O, idx, hmax, hmin, Pbuf, Qbuf);
    k_redstats<<<a.O, 256, 0, stream>>>(Pbuf, Qbuf, a.g, a.b, (float)(BN_ * NPTS * KNB),
                                        scale, shift);
    k_apply<<<TOTP * a.O / 256, 256, 0, stream>>>(hmax, hmin, scale, shift, F + a.colout, a.O);
  }

  // final: PF = F(8192x512) * W5^T(512x1024), split-K=2 via grid.z
  k_gemm128<<<dim3(1024 / 128, TOTP / 128, 2), 256, 0, stream>>>(F, 512, 512, W5, PF, 1024);
  k_fstats<<<64, 256, 0, stream>>>(PF, Fb, Qb);
  k_red5<<<1024, 64, 0, stream>>>(Fb, Qb, g5, b5, sc5, sh5);

  float* out0 = (float*)d_out;
  float* gout = out0 + (size_t)BN_ * 1024 * 128;
  k_out0<<<dim3(16, 2, BN_), 256, 0, stream>>>(PF, sc5, sh5, out0);
  k_gmax<<<dim3(4, 16, BN_), 256, 0, stream>>>(PF, sc5, sh5, tmpmax);
  k_gdup<<<dim3(16, BN_), 256, 0, stream>>>(tmpmax, gout);
}

// Round 19
// 826.140 us; speedup vs baseline: 1.0153x; 1.0153x over previous
//
#include <hip/hip_runtime.h>
#include <cstdint>
#include <cmath>

#define BN_ 4
#define NPTS 2048
#define KNB 20
#define TOTP (BN_ * NPTS)   // 8192

// ---------------- transpose x (B,3,N) -> P0 (B*N, 3)
__global__ void k_transpose(const float* __restrict__ x, float* __restrict__ P0) {
  int i = blockIdx.x * 256 + threadIdx.x;
  if (i >= TOTP) return;
  int b = i / NPTS, n = i % NPTS;
#pragma unroll
  for (int c = 0; c < 3; ++c)
    P0[i * 3 + c] = x[((size_t)b * 3 + c) * NPTS + n];
}

// ---------------- squared norms per point
__global__ void k_sqnorm(const float* __restrict__ base, int ld, int C, float* __restrict__ xx) {
  int i = blockIdx.x * 256 + threadIdx.x;
  if (i >= TOTP) return;
  const float* r = base + (size_t)i * ld;
  float s = 0.f;
  for (int c = 0; c < C; ++c) s = fmaf(r[c], r[c], s);
  xx[i] = s;
}

// ---------------- Symmetric Gram, float4-scalar register prefetch, (256,2)
// (R17 exact; bitwise-frozen: feeds KNN)
__global__ __launch_bounds__(256, 2) void k_gram128(const float* __restrict__ A_all, int lda,
                                                    int K, float* __restrict__ G4) {
  __shared__ float As[2][8][128];
  __shared__ float Bs[2][8][128];
  const int T = NPTS / 128;  // 16
  int q = blockIdx.x;
  int bi = 0;
  while (q >= T - bi) { q -= T - bi; ++bi; }
  int bj = bi + q;
  int b = blockIdx.z;
  const float* A = A_all + (size_t)b * NPTS * lda;
  float* G = G4 + (size_t)b * NPTS * NPTS;
  int tid = threadIdx.x;
  int i0 = bi * 128, m0 = bj * 128;
  int tx = tid & 15, ty = tid >> 4;
  int lr = tid >> 1;          // 0..127
  int lc = (tid & 1) * 4;     // 0 or 4
  const float* Arow = A + (size_t)(i0 + lr) * lda;
  const float* Brow = A + (size_t)(m0 + lr) * lda;
  float acc[2][2][4][4] = {};
  float4 pa, pb;

  pa = *(const float4*)(Arow + lc);
  pb = *(const float4*)(Brow + lc);
  As[0][lc + 0][lr] = pa.x; As[0][lc + 1][lr] = pa.y;
  As[0][lc + 2][lr] = pa.z; As[0][lc + 3][lr] = pa.w;
  Bs[0][lc + 0][lr] = pb.x; Bs[0][lc + 1][lr] = pb.y;
  Bs[0][lc + 2][lr] = pb.z; Bs[0][lc + 3][lr] = pb.w;
  __syncthreads();
  for (int k0 = 0; k0 < K; k0 += 8) {
    int cur = (k0 >> 3) & 1;
    bool more = (k0 + 8 < K);
    if (more) {
      pa = *(const float4*)(Arow + k0 + 8 + lc);
      pb = *(const float4*)(Brow + k0 + 8 + lc);
    }
#pragma unroll
    for (int k = 0; k < 8; ++k) {
      float4 a0 = *(const float4*)&As[cur][k][ty * 4];
      float4 a1 = *(const float4*)&As[cur][k][64 + ty * 4];
      float4 b0 = *(const float4*)&Bs[cur][k][tx * 4];
      float4 b1 = *(const float4*)&Bs[cur][k][64 + tx * 4];
      float ar[2][4] = {{a0.x, a0.y, a0.z, a0.w}, {a1.x, a1.y, a1.z, a1.w}};
      float br[2][4] = {{b0.x, b0.y, b0.z, b0.w}, {b1.x, b1.y, b1.z, b1.w}};
#pragma unroll
      for (int gi = 0; gi < 2; ++gi)
#pragma unroll
        for (int gj = 0; gj < 2; ++gj)
#pragma unroll
          for (int ii = 0; ii < 4; ++ii)
#pragma unroll
            for (int jj = 0; jj < 4; ++jj)
              acc[gi][gj][ii][jj] = fmaf(ar[gi][ii], br[gj][jj], acc[gi][gj][ii][jj]);
    }
    if (more) {
      int nxt = cur ^ 1;
      As[nxt][lc + 0][lr] = pa.x; As[nxt][lc + 1][lr] = pa.y;
      As[nxt][lc + 2][lr] = pa.z; As[nxt][lc + 3][lr] = pa.w;
      Bs[nxt][lc + 0][lr] = pb.x; Bs[nxt][lc + 1][lr] = pb.y;
      Bs[nxt][lc + 2][lr] = pb.z; Bs[nxt][lc + 3][lr] = pb.w;
    }
    __syncthreads();
  }
#pragma unroll
  for (int gi = 0; gi < 2; ++gi)
#pragma unroll
    for (int ii = 0; ii < 4; ++ii) {
      int row = i0 + gi * 64 + ty * 4 + ii;
      float* cr = G + (size_t)row * NPTS + m0;
#pragma unroll
      for (int gj = 0; gj < 2; ++gj) {
        float4 vv = {acc[gi][gj][ii][0], acc[gi][gj][ii][1],
                     acc[gi][gj][ii][2], acc[gi][gj][ii][3]};
        *(float4*)(cr + gj * 64 + tx * 4) = vv;
      }
    }
  if (bi != bj) {
#pragma unroll
    for (int gj = 0; gj < 2; ++gj)
#pragma unroll
      for (int jj = 0; jj < 4; ++jj) {
        int col = m0 + gj * 64 + tx * 4 + jj;
#pragma unroll
        for (int gi = 0; gi < 2; ++gi) {
          float4 vv = {acc[gi][gj][0][jj], acc[gi][gj][1][jj],
                       acc[gi][gj][2][jj], acc[gi][gj][3][jj]};
          *(float4*)(G + (size_t)col * NPTS + i0 + gi * 64 + ty * 4) = vv;
        }
      }
  }
}

// ---------------- GEMM 128x128, 8x8 micro, BK=8, float4-scalar register prefetch.
// Final GEMM only: mode 0, lda=K=512. (R14 proven: VGPR 120, no scratch, ~117 us.)
__global__ __launch_bounds__(256, 2) void k_gemm128(const float* __restrict__ A, int lda, int K,
                                                    const float* __restrict__ W,
                                                    float* __restrict__ Cout, int ldc) {
  __shared__ float As[2][8][128];
  __shared__ float Bs[2][8][128];
  int tid = threadIdx.x;
  int i0 = blockIdx.y * 128, j0 = blockIdx.x * 128;
  int tx = tid & 15, ty = tid >> 4;
  int lr = tid >> 1;
  int lc = (tid & 1) * 4;
  const float* Arow = A + (size_t)(i0 + lr) * lda;
  const float* Wrow = W + (size_t)(j0 + lr) * K;
  float acc[2][2][4][4] = {};
  float4 pa, pw;

  pa = *(const float4*)(Arow + lc);
  pw = *(const float4*)(Wrow + lc);
  As[0][lc + 0][lr] = pa.x; As[0][lc + 1][lr] = pa.y;
  As[0][lc + 2][lr] = pa.z; As[0][lc + 3][lr] = pa.w;
  Bs[0][lc + 0][lr] = pw.x; Bs[0][lc + 1][lr] = pw.y;
  Bs[0][lc + 2][lr] = pw.z; Bs[0][lc + 3][lr] = pw.w;
  __syncthreads();
  for (int k0 = 0; k0 < K; k0 += 8) {
    int cur = (k0 >> 3) & 1;
    bool more = (k0 + 8 < K);
    if (more) {
      pa = *(const float4*)(Arow + k0 + 8 + lc);
      pw = *(const float4*)(Wrow + k0 + 8 + lc);
    }
#pragma unroll
    for (int k = 0; k < 8; ++k) {
      float4 a0 = *(const float4*)&As[cur][k][ty * 4];
      float4 a1 = *(const float4*)&As[cur][k][64 + ty * 4];
      float4 b0 = *(const float4*)&Bs[cur][k][tx * 4];
      float4 b1 = *(const float4*)&Bs[cur][k][64 + tx * 4];
      float ar[2][4] = {{a0.x, a0.y, a0.z, a0.w}, {a1.x, a1.y, a1.z, a1.w}};
      float br[2][4] = {{b0.x, b0.y, b0.z, b0.w}, {b1.x, b1.y, b1.z, b1.w}};
#pragma unroll
      for (int gi = 0; gi < 2; ++gi)
#pragma unroll
        for (int gj = 0; gj < 2; ++gj)
#pragma unroll
          for (int ii = 0; ii < 4; ++ii)
#pragma unroll
            for (int jj = 0; jj < 4; ++jj)
              acc[gi][gj][ii][jj] = fmaf(ar[gi][ii], br[gj][jj], acc[gi][gj][ii][jj]);
    }
    if (more) {
      int nxt = cur ^ 1;
      As[nxt][lc + 0][lr] = pa.x; As[nxt][lc + 1][lr] = pa.y;
      As[nxt][lc + 2][lr] = pa.z; As[nxt][lc + 3][lr] = pa.w;
      Bs[nxt][lc + 0][lr] = pw.x; Bs[nxt][lc + 1][lr] = pw.y;
      Bs[nxt][lc + 2][lr] = pw.z; Bs[nxt][lc + 3][lr] = pw.w;
    }
    __syncthreads();
  }
#pragma unroll
  for (int gi = 0; gi < 2; ++gi)
#pragma unroll
    for (int ii = 0; ii < 4; ++ii) {
      int row = i0 + gi * 64 + ty * 4 + ii;
      float* cr = Cout + (size_t)row * ldc + j0;
#pragma unroll
      for (int gj = 0; gj < 2; ++gj) {
        float4 vv = {acc[gi][gj][ii][0], acc[gi][gj][ii][1],
                     acc[gi][gj][ii][2], acc[gi][gj][ii][3]};
        *(float4*)(cr + gj * 64 + tx * 4) = vv;
      }
    }
}

// ---------------- GEMM 64Mx128N, 4x8 micro, BK=8 dbuf (layer GEMMs; bitwise-frozen)
__global__ __launch_bounds__(256, 4) void k_gemm64(const float* __restrict__ A, int lda, int K,
                                                   const float* __restrict__ W, int mode, int O,
                                                   int twoC, float* __restrict__ Cout, int ldc) {
  __shared__ float As[2][8][64];
  __shared__ float Bs[2][8][128];
  int tid = threadIdx.x;
  int i0 = blockIdx.y * 64, j0 = blockIdx.x * 128;
  int tx = tid & 15, ty = tid >> 4;
  int lrB = tid >> 1;
  int lcB = (tid & 1) * 4;
  int lrA = tid >> 2;
  int lcA = (tid & 3) * 2;
  const float* ArowA = A + (size_t)(i0 + lrA) * lda;
  int j = j0 + lrB;
  float acc[2][4][4] = {};

  auto stage = [&](int buf, int k0) {
    if ((lda & 1) == 0 && k0 + lcA + 2 <= K) {
      float2 av = *(const float2*)(ArowA + k0 + lcA);
      As[buf][lcA + 0][lrA] = av.x;
      As[buf][lcA + 1][lrA] = av.y;
    } else {
#pragma unroll
      for (int u = 0; u < 2; ++u) {
        int k = k0 + lcA + u;
        As[buf][lcA + u][lrA] = (k < K) ? ArowA[k] : 0.f;
      }
    }
#pragma unroll
    for (int u = 0; u < 4; ++u) {
      int k = k0 + lcB + u;
      float wv = 0.f;
      if (k < K) {
        if (mode == 0) wv = W[(size_t)j * K + k];
        else if (j < O) wv = W[(size_t)j * twoC + k];
        else { const float* wr = W + (size_t)(j - O) * twoC; wv = wr[K + k] - wr[k]; }
      }
      Bs[buf][lcB + u][lrB] = wv;
    }
  };

  stage(0, 0);
  __syncthreads();
  for (int k0 = 0; k0 < K; k0 += 8) {
    int cur = (k0 >> 3) & 1;
    if (k0 + 8 < K) stage(cur ^ 1, k0 + 8);
#pragma unroll
    for (int k = 0; k < 8; ++k) {
      float4 a0 = *(const float4*)&As[cur][k][ty * 4];
      float4 b0 = *(const float4*)&Bs[cur][k][tx * 4];
      float4 b1 = *(const float4*)&Bs[cur][k][64 + tx * 4];
      float ar[4] = {a0.x, a0.y, a0.z, a0.w};
      float br[2][4] = {{b0.x, b0.y, b0.z, b0.w}, {b1.x, b1.y, b1.z, b1.w}};
#pragma unroll
      for (int gj = 0; gj < 2; ++gj)
#pragma unroll
        for (int ii = 0; ii < 4; ++ii)
#pragma unroll
          for (int jj = 0; jj < 4; ++jj)
            acc[gj][ii][jj] = fmaf(ar[ii], br[gj][jj], acc[gj][ii][jj]);
    }
    __syncthreads();
  }
#pragma unroll
  for (int ii = 0; ii < 4; ++ii) {
    int row = i0 + ty * 4 + ii;
    float* cr = Cout + (size_t)row * ldc + j0;
#pragma unroll
    for (int gj = 0; gj < 2; ++gj) {
      float4 vv = {acc[gj][ii][0], acc[gj][ii][1], acc[gj][ii][2], acc[gj][ii][3]};
      *(float4*)(cr + gj * 64 + tx * 4) = vv;
    }
  }
}

// ---------------- top-20 (layers 2-4): register-resident (bitwise-frozen)
__global__ __launch_bounds__(256) void k_topk(const float* __restrict__ G4,
                                              const float* __restrict__ xx,
                                              int* __restrict__ idx) {
  int tid = threadIdx.x, w = tid >> 6, lane = tid & 63;
  int b = blockIdx.y;
  int n = blockIdx.x * 4 + w;
  const float* Gr = G4 + (size_t)b * NPTS * NPTS + (size_t)n * NPTS;
  const float* xxb = xx + b * NPTS;
  int* idxb = idx + ((size_t)b * NPTS + n) * KNB;
  float xn = xxb[n];
  float v[32];
#pragma unroll
  for (int t = 0; t < 32; ++t) {
    int m = lane + (t << 6);
    v[t] = 2.f * Gr[m] - xn - xxb[m];
  }
  for (int r = 0; r < KNB; ++r) {
    float bv = v[0]; int bt = 0;
#pragma unroll
    for (int t = 1; t < 32; ++t)
      if (v[t] > bv) { bv = v[t]; bt = t; }
    int bm = lane + (bt << 6);
    float cv = bv; int cm = bm;
#pragma unroll
    for (int off = 32; off; off >>= 1) {
      float ov = __shfl_xor(cv, off, 64);
      int om = __shfl_xor(cm, off, 64);
      if (ov > cv || (ov == cv && om < cm)) { cv = ov; cm = om; }
    }
    if (lane == 0) idxb[r] = cm;
    bool mine = (cm == bm);
#pragma unroll
    for (int t = 0; t < 32; ++t)
      if (mine && t == bt) v[t] = -__builtin_inff();
  }
}

// ---------------- top-20 for layer 1 (K=3): direct distance (bitwise-frozen)
__global__ __launch_bounds__(256) void k_topk3(const float* __restrict__ P0,
                                               const float* __restrict__ xx,
                                               int* __restrict__ idx) {
  int tid = threadIdx.x, w = tid >> 6, lane = tid & 63;
  int b = blockIdx.y;
  int n = blockIdx.x * 4 + w;
  const float* Pb = P0 + (size_t)b * NPTS * 3;
  const float* xxb = xx + b * NPTS;
  int* idxb = idx + ((size_t)b * NPTS + n) * KNB;
  float xn0 = Pb[n * 3 + 0], xn1 = Pb[n * 3 + 1], xn2 = Pb[n * 3 + 2];
  float xn = xxb[n];
  float v[32];
#pragma unroll
  for (int t = 0; t < 32; ++t) {
    int m = lane + (t << 6);
    const float* pm = Pb + m * 3;
    float dot = fmaf(xn2, pm[2], fmaf(xn1, pm[1], fmaf(xn0, pm[0], 0.f)));
    v[t] = 2.f * dot - xn - xxb[m];
  }
  for (int r = 0; r < KNB; ++r) {
    float bv = v[0]; int bt = 0;
#pragma unroll
    for (int t = 1; t < 32; ++t)
      if (v[t] > bv) { bv = v[t]; bt = t; }
    int bm = lane + (bt << 6);
    float cv = bv; int cm = bm;
#pragma unroll
    for (int off = 32; off; off >>= 1) {
      float ov = __shfl_xor(cv, off, 64);
      int om = __shfl_xor(cm, off, 64);
      if (ov > cv || (ov == cv && om < cm)) { cv = ov; cm = om; }
    }
    if (lane == 0) idxb[r] = cm;
    bool mine = (cm == bm);
#pragma unroll
    for (int t = 0; t < 32; ++t)
      if (mine && t == bt) v[t] = -__builtin_inff();
  }
}

// ---------------- gather neighbors (frozen)
__global__ void k_gather(const float* __restrict__ YS, int twoO, int O,
                         const int* __restrict__ idx,
                         float* __restrict__ hmax, float* __restrict__ hmin,
                         double* __restrict__ Pbuf, double* __restrict__ Qbuf) {
  __shared__ float ps[4][256];
  __shared__ float pq[4][256];
  int tid = threadIdx.x, w = tid >> 6, lane = tid & 63;
  int i = blockIdx.x * 4 + w;
  int b = i / NPTS;
  int Q = O >> 6;  // 1,1,2,4
  float s[4], hx[4], hn[4], sm[4], sq[4];
  const float* Srow = YS + (size_t)i * twoO + O;
#pragma unroll
  for (int q = 0; q < 4; ++q) {
    if (q < Q) s[q] = Srow[lane + 64 * q];
    hx[q] = -__builtin_inff(); hn[q] = __builtin_inff(); sm[q] = 0.f; sq[q] = 0.f;
  }
  const int* ip = idx + (size_t)i * KNB;
  for (int k = 0; k < KNB; ++k) {
    int m = ip[k];
    const float* Yrow = YS + (size_t)(b * NPTS + m) * twoO;
#pragma unroll
    for (int q = 0; q < 4; ++q) {
      if (q < Q) {
        float h = Yrow[lane + 64 * q] + s[q];
        hx[q] = fmaxf(hx[q], h);
        hn[q] = fminf(hn[q], h);
        sm[q] += h;
        sq[q] = fmaf(h, h, sq[q]);
      }
    }
  }
#pragma unroll
  for (int q = 0; q < 4; ++q) {
    if (q < Q) {
      int o = lane + 64 * q;
      hmax[(size_t)i * O + o] = hx[q];
      hmin[(size_t)i * O + o] = hn[q];
      ps[w][o] = sm[q];
      pq[w][o] = sq[q];
    }
  }
  __syncthreads();
  if (tid < O) {
    double t1 = (double)(ps[0][tid] + ps[1][tid] + ps[2][tid] + ps[3][tid]);
    double t2 = (double)(pq[0][tid] + pq[1][tid] + pq[2][tid] + pq[3][tid]);
    Pbuf[(size_t)tid * 2048 + blockIdx.x] = t1;
    Qbuf[(size_t)tid * 2048 + blockIdx.x] = t2;
  }
}

// ---------------- deterministic reduce of 2048 partials per channel (frozen)
__global__ __launch_bounds__(256) void k_redstats(const double* __restrict__ Pbuf,
                                                  const double* __restrict__ Qbuf,
                                                  const float* __restrict__ g,
                                                  const float* __restrict__ bb, float cnt,
                                                  float* __restrict__ scale,
                                                  float* __restrict__ shift) {
  __shared__ double s1[256], s2[256];
  int o = blockIdx.x, t = threadIdx.x;
  double a = 0.0, c = 0.0;
#pragma unroll
  for (int j = 0; j < 8; ++j) {
    a += Pbuf[(size_t)o * 2048 + t + 256 * j];
    c += Qbuf[(size_t)o * 2048 + t + 256 * j];
  }
  s1[t] = a; s2[t] = c;
  __syncthreads();
  for (int s = 128; s; s >>= 1) {
    if (t < s) { s1[t] += s1[t + s]; s2[t] += s2[t + s]; }
    __syncthreads();
  }
  if (t == 0) {
    double mean = s1[0] / (double)cnt;
    double var = s2[0] / (double)cnt - mean * mean;
    double sc = (double)g[o] / sqrt(var + 1e-5);
    scale[o] = (float)sc;
    shift[o] = (float)((double)bb[o] - mean * sc);
  }
}

// ---------------- apply BN+lrelu (frozen)
__global__ void k_apply(const float* __restrict__ hmax, const float* __restrict__ hmin,
                        const float* __restrict__ scale, const float* __restrict__ shift,
                        float* __restrict__ Fout, int O) {
  int t = blockIdx.x * 256 + threadIdx.x;
  int i = t / O, o = t % O;
  float sc = scale[o];
  float h = (sc >= 0.f) ? hmax[t] : hmin[t];
  float v = fmaf(sc, h, shift[o]);
  Fout[(size_t)i * 512 + o] = (v >= 0.f) ? v : 0.2f * v;
}

// ---------------- final BN partials (frozen)
__global__ void k_fstats(const float* __restrict__ PF, double* __restrict__ Fb,
                         double* __restrict__ Qb) {
  int tid = threadIdx.x, bid = blockIdx.x;
  float sm[4] = {0.f, 0.f, 0.f, 0.f}, sq[4] = {0.f, 0.f, 0.f, 0.f};
  int r0 = bid * 128;
  for (int r = 0; r < 128; ++r) {
    const float* row = PF + (size_t)(r0 + r) * 1024;
#pragma unroll
    for (int q = 0; q < 4; ++q) {
      float v = row[tid + 256 * q];
      sm[q] += v;
      sq[q] = fmaf(v, v, sq[q]);
    }
  }
#pragma unroll
  for (int q = 0; q < 4; ++q) {
    int o = tid + 256 * q;
    Fb[(size_t)o * 64 + bid] = (double)sm[q];
    Qb[(size_t)o * 64 + bid] = (double)sq[q];
  }
}

// ---------------- deterministic reduce -> sc5/sh5 (frozen)
__global__ __launch_bounds__(64) void k_red5(const double* __restrict__ Fb,
                                             const double* __restrict__ Qb,
                                             const float* __restrict__ g,
                                             const float* __restrict__ bb,
                                             float* __restrict__ sc5, float* __restrict__ sh5) {
  __shared__ double s1[64], s2[64];
  int o = blockIdx.x, t = threadIdx.x;
  s1[t] = Fb[(size_t)o * 64 + t];
  s2[t] = Qb[(size_t)o * 64 + t];
  __syncthreads();
  for (int s = 32; s; s >>= 1) {
    if (t < s) { s1[t] += s1[t + s]; s2[t] += s2[t + s]; }
    __syncthreads();
  }
  if (t == 0) {
    double cnt = (double)TOTP;
    double mean = s1[0] / cnt;
    double var = s2[0] / cnt - mean * mean;
    double sc = (double)g[o] / sqrt(var + 1e-5);
    sc5[o] = (float)sc;
    sh5[o] = (float)((double)bb[o] - mean * sc);
  }
}

// ---------------- out0 (frozen)
__global__ void k_out0(const float* __restrict__ PF, const float* __restrict__ sc5,
                       const float* __restrict__ sh5, float* __restrict__ out0) {
  __shared__ float t[64][65];
  int b = blockIdx.z, p0 = blockIdx.y * 64, o0 = blockIdx.x * 64;
  int ol = threadIdx.x & 63, pg = threadIdx.x >> 6;
#pragma unroll
  for (int q = 0; q < 16; ++q) {
    int p = q * 4 + pg;
    t[p][ol] = PF[((size_t)(b * NPTS + p0 + p)) * 1024 + o0 + ol];
  }
  __syncthreads();
#pragma unroll
  for (int q = 0; q < 16; ++q) {
    int oo = q * 4 + pg;
    int o = o0 + oo;
    float v = fmaf(sc5[o], t[ol][oo], sh5[o]);
    float a = (v >= 0.f) ? v : 0.2f * v;
    out0[((size_t)(b * 1024 + o)) * 128 + p0 + ol] = a;
  }
}

// ---------------- per-(b,nb,o) max (frozen)
__global__ void k_gmax(const float* __restrict__ PF, const float* __restrict__ sc5,
                       const float* __restrict__ sh5, float* __restrict__ tmpmax) {
  int b = blockIdx.z, nb = blockIdx.y;
  int o = blockIdx.x * 256 + threadIdx.x;
  const float* base = PF + ((size_t)(b * NPTS + nb * 128)) * 1024 + o;
  float sc = sc5[o], sh = sh5[o];
  float m0 = -__builtin_inff(), m1 = m0, m2 = m0, m3 = m0;
  for (int p = 0; p < 128; p += 4) {
    float v0 = base[(size_t)(p + 0) * 1024];
    float v1 = base[(size_t)(p + 1) * 1024];
    float v2 = base[(size_t)(p + 2) * 1024];
    float v3 = base[(size_t)(p + 3) * 1024];
    float a0 = fmaf(sc, v0, sh); a0 = (a0 >= 0.f) ? a0 : 0.2f * a0;
    float a1 = fmaf(sc, v1, sh); a1 = (a1 >= 0.f) ? a1 : 0.2f * a1;
    float a2 = fmaf(sc, v2, sh); a2 = (a2 >= 0.f) ? a2 : 0.2f * a2;
    float a3 = fmaf(sc, v3, sh); a3 = (a3 >= 0.f) ? a3 : 0.2f * a3;
    m0 = fmaxf(m0, a0); m1 = fmaxf(m1, a1);
    m2 = fmaxf(m2, a2); m3 = fmaxf(m3, a3);
  }
  tmpmax[(size_t)(b * 16 + nb) * 1024 + o] = fmaxf(fmaxf(m0, m1), fmaxf(m2, m3));
}

// ---------------- gout duplication (frozen)
__global__ void k_gdup(const float* __restrict__ tmpmax, float* __restrict__ gout) {
  __shared__ float t[16][65];
  int b = blockIdx.y, o0 = blockIdx.x * 64;
  int ol = threadIdx.x & 63, ng = threadIdx.x >> 6;
#pragma unroll
  for (int q = 0; q < 4; ++q) {
    int nb = q * 4 + ng;
    t[nb][ol] = tmpmax[(size_t)(b * 16 + nb) * 1024 + o0 + ol];
  }
  __syncthreads();
  int nb2 = threadIdx.x & 15, og = threadIdx.x >> 4;
#pragma unroll
  for (int q = 0; q < 4; ++q) {
    int oo = q * 16 + og;
    float v = t[nb2][oo];
    size_t base = ((size_t)(b * 2048) + o0 + oo) * 16 + nb2;
    gout[base] = v;
    gout[base + 1024 * 16] = v;
  }
}

extern "C" void kernel_launch(void* const* d_in, const int* in_sizes, int n_in,
                              void* d_out, int out_size, void* d_ws, size_t ws_size,
                              hipStream_t stream) {
  const float* x  = (const float*)d_in[0];
  const float* W1 = (const float*)d_in[1];
  const float* W2 = (const float*)d_in[2];
  const float* W3 = (const float*)d_in[3];
  const float* W4 = (const float*)d_in[4];
  const float* W5 = (const float*)d_in[5];
  const float* g1 = (const float*)d_in[6];  const float* b1 = (const float*)d_in[7];
  const float* g2 = (const float*)d_in[8];  const float* b2 = (const float*)d_in[9];
  const float* g3 = (const float*)d_in[10]; const float* b3 = (const float*)d_in[11];
  const float* g4 = (const float*)d_in[12]; const float* b4 = (const float*)d_in[13];
  const float* g5 = (const float*)d_in[14]; const float* b5 = (const float*)d_in[15];

  float* ws = (float*)d_ws;
  size_t off = 0;
  auto alloc = [&](size_t nfl) { float* p = ws + off; off += (nfl + 63) & ~(size_t)63; return p; };
  float*  P0   = alloc((size_t)TOTP * 3);
  float*  F    = alloc((size_t)TOTP * 512);
  float*  xx   = alloc(TOTP);
  // Union U (16.78M floats): G4 lives during gram+topk of layers 2-4;
  // YS/hmax/hmin live during gemm..apply; PF lives after the last topk.
  float*  U    = alloc((size_t)BN_ * NPTS * NPTS);
  float*  G4   = U;
  float*  YS   = U;
  float*  hmax = U + (size_t)TOTP * 512;
  float*  hmin = hmax + (size_t)TOTP * 256;
  float*  PF   = hmin + (size_t)TOTP * 256;
  float*  tmpmax = alloc((size_t)BN_ * 16 * 1024);
  double* Pbuf = (double*)alloc((size_t)256 * 2048 * 2);
  double* Qbuf = (double*)alloc((size_t)256 * 2048 * 2);
  double* Fb   = (double*)alloc((size_t)1024 * 64 * 2);
  double* Qb   = (double*)alloc((size_t)1024 * 64 * 2);
  float*  scale= alloc(256);
  float*  shift= alloc(256);
  float*  sc5  = alloc(1024);
  float*  sh5  = alloc(1024);
  int*    idx  = (int*)alloc((size_t)TOTP * KNB);

  k_transpose<<<32, 256, 0, stream>>>(x, P0);

  struct L { const float* base; int lda, C, O, colout; const float* W; const float* g; const float* b; };
  L Ls[4] = {
    {P0,      3,   3,   64,  0,   W1, g1, b1},
    {F,       512, 64,  64,  64,  W2, g2, b2},
    {F + 64,  512, 64,  128, 128, W3, g3, b3},
    {F + 128, 512, 128, 256, 256, W4, g4, b4},
  };

  for (int l = 0; l < 4; ++l) {
    const L& a = Ls[l];
    k_sqnorm<<<32, 256, 0, stream>>>(a.base, a.lda, a.C, xx);
    if (l == 0) {
      k_topk3<<<dim3(512, BN_), 256, 0, stream>>>(P0, xx, idx);
    } else {
      k_gram128<<<dim3(136, 1, BN_), 256, 0, stream>>>(a.base, a.lda, a.C, G4);
      k_topk<<<dim3(512, BN_), 256, 0, stream>>>(G4, xx, idx);
    }
    int twoO = 2 * a.O;
    k_gemm64<<<dim3(twoO / 128, TOTP / 64), 256, 0, stream>>>(
        a.base, a.lda, a.C, a.W, 1, a.O, 2 * a.C, YS, twoO);
    k_gather<<<TOTP / 4, 256, 0, stream>>>(YS, twoO, a.O, idx, hmax, hmin, Pbuf, Qbuf);
    k_redstats<<<a.O, 256, 0, stream>>>(Pbuf, Qbuf, a.g, a.b, (float)(BN_ * NPTS * KNB),
                                        scale, shift);
    k_apply<<<TOTP * a.O / 256, 256, 0, stream>>>(hmax, hmin, scale, shift, F + a.colout, a.O);
  }

  // final: PF = F(8192x512) * W5^T(512x1024)
  k_gemm128<<<dim3(1024 / 128, TOTP / 128), 256, 0, stream>>>(F, 512, 512, W5, PF, 1024);
  k_fstats<<<64, 256, 0, stream>>>(PF, Fb, Qb);
  k_red5<<<1024, 64, 0, stream>>>(Fb, Qb, g5, b5, sc5, sh5);

  float* out0 = (float*)d_out;
  float* gout = out0 + (size_t)BN_ * 1024 * 128;
  k_out0<<<dim3(16, 2, BN_), 256, 0, stream>>>(PF, sc5, sh5, out0);
  k_gmax<<<dim3(4, 16, BN_), 256, 0, stream>>>(PF, sc5, sh5, tmpmax);
  k_gdup<<<dim3(16, BN_), 256, 0, stream>>>(tmpmax, gout);
}